// Round 7
// baseline (937.355 us; speedup 1.0000x reference)
//
#include <hip/hip_runtime.h>
#include <hip/hip_bf16.h>
#include <math.h>

#define N_NODES 100000
#define N_EDGES 1600000
#define F_IN 64
#define H_DIM 200
#define N_GRAPHS 512
#define NB_SCAN 98   // ceil(100000 / 1024)

#define WT_PER (224 * 224)   // one padded weight table (shorts)
#define SA 232               // LDS A-tile stride (shorts)

typedef __attribute__((ext_vector_type(8))) short short8v;   // 8 bf16 = 4 VGPR
typedef __attribute__((ext_vector_type(4))) float f32x4;     // mfma accumulator

// ---------------- CSR build: histogram by dst ----------------
__global__ void hist_kernel(const int* __restrict__ ei, int* __restrict__ cnt) {
    int i = blockIdx.x * blockDim.x + threadIdx.x;
    if (i < N_EDGES) atomicAdd(&cnt[ei[N_EDGES + i]], 1);
}

__global__ __launch_bounds__(256) void scan_part(const int* __restrict__ deg,
                                                 int* __restrict__ bsums) {
    int b = blockIdx.x, t = threadIdx.x;
    int i0 = b * 1024 + t * 4;
    int s = 0;
    #pragma unroll
    for (int k = 0; k < 4; ++k) { int i = i0 + k; if (i < N_NODES) s += deg[i]; }
    #pragma unroll
    for (int off = 32; off > 0; off >>= 1) s += __shfl_down(s, off, 64);
    __shared__ int wsum[4];
    if ((t & 63) == 0) wsum[t >> 6] = s;
    __syncthreads();
    if (t == 0) bsums[b] = wsum[0] + wsum[1] + wsum[2] + wsum[3];
}

__global__ void scan_tops(int* __restrict__ bsums, int* __restrict__ ptr) {
    __shared__ int sh[128];
    int t = threadIdx.x;
    int v = (t < NB_SCAN) ? bsums[t] : 0;
    sh[t] = v;
    __syncthreads();
    for (int off = 1; off < 128; off <<= 1) {
        int a = sh[t];
        int add = (t >= off) ? sh[t - off] : 0;
        __syncthreads();
        sh[t] = a + add;
        __syncthreads();
    }
    if (t < NB_SCAN) bsums[t] = sh[t] - v;
    if (t == 127) ptr[N_NODES] = sh[127];
}

__global__ __launch_bounds__(256) void scan_fin(int* __restrict__ deg_cursor,
                                                const int* __restrict__ bsums,
                                                int* __restrict__ ptr) {
    int b = blockIdx.x, t = threadIdx.x;
    int i0 = b * 1024 + t * 4;
    int d[4]; int s = 0;
    #pragma unroll
    for (int k = 0; k < 4; ++k) {
        int i = i0 + k;
        d[k] = (i < N_NODES) ? deg_cursor[i] : 0;
        s += d[k];
    }
    __shared__ int sh[256];
    sh[t] = s;
    __syncthreads();
    for (int off = 1; off < 256; off <<= 1) {
        int a = sh[t];
        int add = (t >= off) ? sh[t - off] : 0;
        __syncthreads();
        sh[t] = a + add;
        __syncthreads();
    }
    int run = bsums[b] + sh[t] - s;
    #pragma unroll
    for (int k = 0; k < 4; ++k) {
        int i = i0 + k;
        if (i < N_NODES) { ptr[i] = run; deg_cursor[i] = run; run += d[k]; }
    }
}

__global__ void fill_kernel(const int* __restrict__ ei, int* __restrict__ cursor,
                            int* __restrict__ csr_src) {
    int i = blockIdx.x * blockDim.x + threadIdx.x;
    if (i < N_EDGES) {
        int s = ei[i];
        int d = ei[N_EDGES + i];
        int p = atomicAdd(&cursor[d], 1);
        csr_src[p] = s;
    }
}

// helpers
__device__ __forceinline__ short f2bf(float f) {
    __hip_bfloat16 h = __float2bfloat16(f);
    return *reinterpret_cast<const short*>(&h);
}
__device__ __forceinline__ float bf2f(short s) {
    return __uint_as_float(((unsigned)(unsigned short)s) << 16);
}
__device__ __forceinline__ float4 bf4_to_f4(uint2 u) {
    float4 r;
    r.x = __uint_as_float(u.x << 16);
    r.y = __uint_as_float(u.x & 0xffff0000u);
    r.z = __uint_as_float(u.y << 16);
    r.w = __uint_as_float(u.y & 0xffff0000u);
    return r;
}

// ---------------- X fp32 -> bf16 (halves layer-1 gather bytes) ----------------
__global__ void prep_x(const float* __restrict__ X, short* __restrict__ Xb) {
    int i = blockIdx.x * 256 + threadIdx.x;
    if (i < N_NODES * 64) Xb[i] = f2bf(X[i]);
}

// ---------------- weight prep: W[K][200] fp32 -> hi/lo bf16 tables [224 cols][224 k] ----------------
__global__ void prep_w(const float* __restrict__ W1a, const float* __restrict__ W1b,
                       const float* __restrict__ W2a, const float* __restrict__ W2b,
                       short* __restrict__ wt) {
    int idx = blockIdx.x * 256 + threadIdx.x;
    if (idx >= 4 * WT_PER) return;
    int tsel = idx / WT_PER, rem = idx % WT_PER;
    int c = rem / 224, k = rem % 224;
    const float* W = (tsel == 0) ? W1a : (tsel == 1) ? W1b : (tsel == 2) ? W2a : W2b;
    int K = (tsel == 0) ? 64 : 200;
    float v = (k < K && c < 200) ? W[k * 200 + c] : 0.0f;   // pads MUST be zero
    short hi = f2bf(v);
    short lo = f2bf(v - bf2f(hi));
    wt[(2 * tsel) * WT_PER + rem] = hi;
    wt[(2 * tsel + 1) * WT_PER + rem] = lo;
}

// ---- split-bf16 MFMA tile GEMM ----
// A: row=l&15, k=8*(l>>4)+j ; B: col=l&15, same k ; acc: col=l&15, row=(l>>4)*4+i
// acc += Ah*Bh + Ah*Bl + Al*Bh  (Al*Bl dropped, ~2^-16 relative)
template <int NKS>
__device__ __forceinline__ void gemm_split(const short* __restrict__ SLh,
                                           const short* __restrict__ SLl,
                                           const short* __restrict__ Wh,
                                           const short* __restrict__ Wl,
                                           int l15, int lhi, int rt,
                                           int base, int cnt, f32x4 acc[4]) {
    for (int ks = 0; ks < NKS; ++ks) {
        const int k0 = ks * 32 + 8 * lhi;
        short8v ah = *reinterpret_cast<const short8v*>(SLh + (rt * 16 + l15) * SA + k0);
        short8v al = *reinterpret_cast<const short8v*>(SLl + (rt * 16 + l15) * SA + k0);
        #pragma unroll
        for (int i = 0; i < 4; ++i) {
            if (i < cnt) {
                const int wrow = (base + i) * 16 + l15;
                short8v bh = *reinterpret_cast<const short8v*>(Wh + wrow * 224 + k0);
                short8v bl = *reinterpret_cast<const short8v*>(Wl + wrow * 224 + k0);
                acc[i] = __builtin_amdgcn_mfma_f32_16x16x32_bf16(ah, bh, acc[i], 0, 0, 0);
                acc[i] = __builtin_amdgcn_mfma_f32_16x16x32_bf16(ah, bl, acc[i], 0, 0, 0);
                acc[i] = __builtin_amdgcn_mfma_f32_16x16x32_bf16(al, bh, acc[i], 0, 0, 0);
            }
        }
    }
}

// ---------------- fused GIN layer: gather -> split-MFMA GEMM1 -> relu -> GEMM2 -> BN ----------------
// 1024 threads = 16 waves; 64 nodes/block; LDS 59.4KB -> 2 blocks/CU = 32 waves/CU.
// Gather: each wave owns 4 rows; 4-deep load batches into 2 accumulators
// (spill-free under the 64-reg cap of __launch_bounds__(1024,8) — round-6 lesson).
// GEMM: wave = (row-tile rt = wid>>2) x (col-group cq = wid&3; groups of 4/3/3/3 col-tiles).
template <bool FIRST>
__global__ __launch_bounds__(1024, 8) void gin_mfma(
        const void* __restrict__ Xv,                 // bf16 [N][64] or bf16 [N][200]
        const int* __restrict__ ptr, const int* __restrict__ srcl,
        const float* __restrict__ eps_p,
        const short* __restrict__ Wa2,               // hi table; lo at +WT_PER
        const float* __restrict__ ba,
        const short* __restrict__ Wb2, const float* __restrict__ bb,
        const float* __restrict__ gamma, const float* __restrict__ beta,
        const float* __restrict__ mean, const float* __restrict__ var,
        void* __restrict__ outv) {                   // bf16 [N][200] or fp32 [N][200]
    __shared__ __align__(16) short SLh[64 * SA];     // 29,696 B
    __shared__ __align__(16) short SLl[64 * SA];     // 29,696 B
    const int t = threadIdx.x;
    const int lane = t & 63;
    const int wid = t >> 6;
    const int node0 = blockIdx.x * 64;
    const float ep = 1.0f + eps_p[0];

    // ---- zero the k-pad cols [200,232) so garbage never reaches MFMA ----
    for (int i = t; i < 64 * 32; i += 1024) {
        int row = i >> 5, c = 200 + (i & 31);
        SLh[row * SA + c] = 0;
        SLl[row * SA + c] = 0;
    }

    // ---- gather phase: 4 rows per wave, 4-deep ILP, 2 accumulators ----
    if (FIRST) {
        const short* Xb = (const short*)Xv;          // bf16 [N][64]
        for (int rr = 0; rr < 4; ++rr) {
            int row = wid * 4 + rr;
            int node = node0 + row;
            if (node >= N_NODES) break;
            int b = ptr[node], e = ptr[node + 1];
            float a0 = ep * bf2f(Xb[(size_t)node * 64 + lane]);
            float a1 = 0.f;
            int j = b;
            for (; j + 4 <= e; j += 4) {
                int s0 = srcl[j+0], s1 = srcl[j+1], s2 = srcl[j+2], s3 = srcl[j+3];
                short f0 = Xb[(size_t)s0 * 64 + lane];
                short f1 = Xb[(size_t)s1 * 64 + lane];
                short f2 = Xb[(size_t)s2 * 64 + lane];
                short f3 = Xb[(size_t)s3 * 64 + lane];
                a0 += bf2f(f0) + bf2f(f2);
                a1 += bf2f(f1) + bf2f(f3);
            }
            for (; j < e; ++j) a0 += bf2f(Xb[(size_t)srcl[j] * 64 + lane]);
            float s = a0 + a1;
            short hi = f2bf(s);
            SLh[row * SA + lane] = hi;               // k = lane < 64
            SLl[row * SA + lane] = f2bf(s - bf2f(hi));
        }
    } else {
        const uint2* H2 = (const uint2*)Xv;          // bf16 rows: 50 x uint2
        for (int rr = 0; rr < 4; ++rr) {
            int row = wid * 4 + rr;
            int node = node0 + row;
            if (node >= N_NODES) break;
            int b = ptr[node], e = ptr[node + 1];
            if (lane < 50) {
                float4 fs = bf4_to_f4(H2[(size_t)node * 50 + lane]);
                float4 A0 = make_float4(ep * fs.x, ep * fs.y, ep * fs.z, ep * fs.w);
                float4 A1 = make_float4(0.f, 0.f, 0.f, 0.f);
                int j = b;
                for (; j + 4 <= e; j += 4) {
                    int s0 = srcl[j+0], s1 = srcl[j+1], s2 = srcl[j+2], s3 = srcl[j+3];
                    uint2 u0 = H2[(size_t)s0 * 50 + lane];
                    uint2 u1 = H2[(size_t)s1 * 50 + lane];
                    uint2 u2 = H2[(size_t)s2 * 50 + lane];
                    uint2 u3 = H2[(size_t)s3 * 50 + lane];
                    float4 f0 = bf4_to_f4(u0), f1 = bf4_to_f4(u1);
                    float4 f2 = bf4_to_f4(u2), f3 = bf4_to_f4(u3);
                    A0.x += f0.x + f2.x; A0.y += f0.y + f2.y;
                    A0.z += f0.z + f2.z; A0.w += f0.w + f2.w;
                    A1.x += f1.x + f3.x; A1.y += f1.y + f3.y;
                    A1.z += f1.z + f3.z; A1.w += f1.w + f3.w;
                }
                for (; j < e; ++j) {
                    float4 f0 = bf4_to_f4(H2[(size_t)srcl[j] * 50 + lane]);
                    A0.x += f0.x; A0.y += f0.y; A0.z += f0.z; A0.w += f0.w;
                }
                float sx = A0.x + A1.x;
                float sy = A0.y + A1.y;
                float sz = A0.z + A1.z;
                float sw = A0.w + A1.w;
                short4 ph, pl;
                ph.x = f2bf(sx); pl.x = f2bf(sx - bf2f(ph.x));
                ph.y = f2bf(sy); pl.y = f2bf(sy - bf2f(ph.y));
                ph.z = f2bf(sz); pl.z = f2bf(sz - bf2f(ph.z));
                ph.w = f2bf(sw); pl.w = f2bf(sw - bf2f(ph.w));
                *reinterpret_cast<short4*>(&SLh[row * SA + 4 * lane]) = ph;
                *reinterpret_cast<short4*>(&SLl[row * SA + 4 * lane]) = pl;
            }
        }
    }
    __syncthreads();

    const int l15 = lane & 15;
    const int lhi = lane >> 4;
    const int rt = wid >> 2;                         // row-tile 0..3
    const int cq = wid & 3;                          // col-group 0..3
    const int base = (cq == 0) ? 0 : (4 + 3 * (cq - 1));   // {0,4,7,10}
    const int cnt  = (cq == 0) ? 4 : 3;                    // 4+3+3+3 = 13 col-tiles

    // ---- GEMM1 ----
    f32x4 acc1[4];
    #pragma unroll
    for (int i = 0; i < 4; ++i) acc1[i] = (f32x4){0.f, 0.f, 0.f, 0.f};
    if (FIRST) gemm_split<2>(SLh, SLl, Wa2, Wa2 + WT_PER, l15, lhi, rt, base, cnt, acc1);
    else       gemm_split<7>(SLh, SLl, Wa2, Wa2 + WT_PER, l15, lhi, rt, base, cnt, acc1);
    __syncthreads();   // all A1 reads done before overwrite

    // ---- t = relu(acc1 + ba) -> SLh/SLl (cols < 200; pads still zero) ----
    #pragma unroll
    for (int i = 0; i < 4; ++i) {
        if (i < cnt) {
            int col = (base + i) * 16 + l15;
            if (col < 200) {
                float bv = ba[col];
                #pragma unroll
                for (int r = 0; r < 4; ++r) {
                    int row = rt * 16 + lhi * 4 + r;
                    float v = fmaxf(acc1[i][r] + bv, 0.0f);
                    short hi = f2bf(v);
                    SLh[row * SA + col] = hi;
                    SLl[row * SA + col] = f2bf(v - bf2f(hi));
                }
            }
        }
    }
    __syncthreads();

    // ---- GEMM2 (K = 200 both layers) ----
    f32x4 acc2[4];
    #pragma unroll
    for (int i = 0; i < 4; ++i) acc2[i] = (f32x4){0.f, 0.f, 0.f, 0.f};
    gemm_split<7>(SLh, SLl, Wb2, Wb2 + WT_PER, l15, lhi, rt, base, cnt, acc2);

    // ---- epilogue: relu + BN -> out ----
    #pragma unroll
    for (int i = 0; i < 4; ++i) {
        if (i < cnt) {
            int col = (base + i) * 16 + l15;
            if (col < 200) {
                float bv = bb[col];
                float g0 = gamma[col], bt = beta[col], mn = mean[col];
                float inv = rsqrtf(var[col] + 1e-5f);
                #pragma unroll
                for (int r = 0; r < 4; ++r) {
                    int row = rt * 16 + lhi * 4 + r;
                    int node = node0 + row;
                    if (node < N_NODES) {
                        float v = fmaxf(acc2[i][r] + bv, 0.0f);
                        v = (v - mn) * inv * g0 + bt;
                        if (FIRST) ((__hip_bfloat16*)outv)[(size_t)node * 200 + col] = __float2bfloat16(v);
                        else       ((float*)outv)[(size_t)node * 200 + col] = v;
                    }
                }
            }
        }
    }
}

// ---------------- fused pooling (sum+max) + FC + log_softmax ----------------
__device__ __forceinline__ int lower_bound_dev(const int* a, int n, int v) {
    int lo = 0, hi = n;
    while (lo < hi) { int mid = (lo + hi) >> 1; if (a[mid] < v) lo = mid + 1; else hi = mid; }
    return lo;
}

__global__ __launch_bounds__(256) void pool_fc_kernel(const float* __restrict__ h,
        const int* __restrict__ batch, const float* __restrict__ Wfc,
        const float* __restrict__ bfc, float* __restrict__ out) {
    int g = blockIdx.x;
    __shared__ int range[2];
    if (threadIdx.x == 0) range[0] = lower_bound_dev(batch, N_NODES, g);
    else if (threadIdx.x == 64) range[1] = lower_bound_dev(batch, N_NODES, g + 1);
    __syncthreads();
    int b = range[0], e = range[1];
    int d = threadIdx.x;
    float s = 0.0f, m = -3.0e38f;
    for (int n = b; n < e; ++n) {
        if (d < 200) {
            float v = h[(size_t)n * 200 + d];
            s += v;
            m = fmaxf(m, v);
        }
    }
    float c0 = 0.f, c1 = 0.f;
    if (d < 200) {
        c0 = s * Wfc[d * 2 + 0] + m * Wfc[(200 + d) * 2 + 0];
        c1 = s * Wfc[d * 2 + 1] + m * Wfc[(200 + d) * 2 + 1];
    }
    #pragma unroll
    for (int off = 32; off > 0; off >>= 1) {
        c0 += __shfl_down(c0, off, 64);
        c1 += __shfl_down(c1, off, 64);
    }
    __shared__ float r0[4], r1[4];
    int wid = threadIdx.x >> 6;
    if ((threadIdx.x & 63) == 0) { r0[wid] = c0; r1[wid] = c1; }
    __syncthreads();
    if (threadIdx.x == 0) {
        float l0 = r0[0] + r0[1] + r0[2] + r0[3] + bfc[0];
        float l1 = r1[0] + r1[1] + r1[2] + r1[3] + bfc[1];
        float mx = fmaxf(l0, l1);
        float lse = mx + logf(expf(l0 - mx) + expf(l1 - mx));
        out[g * 2 + 0] = l0 - lse;
        out[g * 2 + 1] = l1 - lse;
    }
}

// ---------------- launch ----------------
extern "C" void kernel_launch(void* const* d_in, const int* in_sizes, int n_in,
                              void* d_out, int out_size, void* d_ws, size_t ws_size,
                              hipStream_t stream) {
    const float* x    = (const float*)d_in[0];
    const int*   ei   = (const int*)d_in[1];
    const int*   batch= (const int*)d_in[2];
    const float* eps1 = (const float*)d_in[3];
    const float* W1a  = (const float*)d_in[4];
    const float* b1a  = (const float*)d_in[5];
    const float* W1b  = (const float*)d_in[6];
    const float* b1b  = (const float*)d_in[7];
    const float* bn1g = (const float*)d_in[8];
    const float* bn1b = (const float*)d_in[9];
    const float* bn1m = (const float*)d_in[10];
    const float* bn1v = (const float*)d_in[11];
    const float* eps2 = (const float*)d_in[12];
    const float* W2a  = (const float*)d_in[13];
    const float* b2a  = (const float*)d_in[14];
    const float* W2b  = (const float*)d_in[15];
    const float* b2b  = (const float*)d_in[16];
    const float* bn2g = (const float*)d_in[17];
    const float* bn2b = (const float*)d_in[18];
    const float* bn2m = (const float*)d_in[19];
    const float* bn2v = (const float*)d_in[20];
    const float* Wfc  = (const float*)d_in[21];
    const float* bfc  = (const float*)d_in[22];
    float* out = (float*)d_out;

    // workspace layout (~141 MB total):
    // [0, 400128)               csr_ptr (N+1 ints)
    // [400128, 800256)          cursor
    // [800256, 7200256)         csr_src (E ints)
    // [7200256, 8003072)        wt: 8 bf16 tables [224][224] (hi/lo x 4 matrices)
    // [8003072, 20803072)       Xb (N x 64 bf16)
    // [20803072, 60803072)      h1b (N x 200 bf16)
    // [60803072, 140803072)     h2  (N x 200 fp32)
    char* ws = (char*)d_ws;
    int* csr_ptr = (int*)(ws + 0);
    int* cursor  = (int*)(ws + 400128);
    int* csr_src = (int*)(ws + 800256);
    short* wt    = (short*)(ws + 7200256);
    short* W1a2 = wt;                    // hi; lo at +WT_PER
    short* W1b2 = wt + 2 * WT_PER;
    short* W2a2 = wt + 4 * WT_PER;
    short* W2b2 = wt + 6 * WT_PER;
    short* Xb    = (short*)(ws + 8003072);
    __hip_bfloat16* h1b = (__hip_bfloat16*)(ws + 20803072);
    float* h2    = (float*)(ws + 60803072);
    int* bsums   = (int*)(ws + 20803072);  // alias h1b: dead until layer1 writes

    hipMemsetAsync(cursor, 0, N_NODES * sizeof(int), stream);
    hist_kernel<<<(N_EDGES + 255) / 256, 256, 0, stream>>>(ei, cursor);
    scan_part<<<NB_SCAN, 256, 0, stream>>>(cursor, bsums);
    scan_tops<<<1, 128, 0, stream>>>(bsums, csr_ptr);
    scan_fin<<<NB_SCAN, 256, 0, stream>>>(cursor, bsums, csr_ptr);
    fill_kernel<<<(N_EDGES + 255) / 256, 256, 0, stream>>>(ei, cursor, csr_src);
    prep_w<<<(4 * WT_PER + 255) / 256, 256, 0, stream>>>(W1a, W1b, W2a, W2b, wt);
    prep_x<<<(N_NODES * 64 + 255) / 256, 256, 0, stream>>>(x, Xb);

    const int NBLK = (N_NODES + 63) / 64;   // 1563
    gin_mfma<true><<<NBLK, 1024, 0, stream>>>(Xb, csr_ptr, csr_src, eps1,
            W1a2, b1a, W1b2, b1b, bn1g, bn1b, bn1m, bn1v, h1b);
    gin_mfma<false><<<NBLK, 1024, 0, stream>>>(h1b, csr_ptr, csr_src, eps2,
            W2a2, b2a, W2b2, b2b, bn2g, bn2b, bn2m, bn2v, h2);

    pool_fc_kernel<<<N_GRAPHS, 256, 0, stream>>>(h2, batch, Wfc, bfc, out);
}

// Round 8
// 856.527 us; speedup vs baseline: 1.0944x; 1.0944x over previous
//
#include <hip/hip_runtime.h>
#include <hip/hip_bf16.h>
#include <math.h>

#define N_NODES 100000
#define N_EDGES 1600000
#define F_IN 64
#define H_DIM 200
#define N_GRAPHS 512
#define NB_SCAN 98   // ceil(100000 / 1024)

#define WT_PER (224 * 224)   // one padded weight table (shorts)
#define SA 232               // LDS A-tile stride (shorts)

typedef __attribute__((ext_vector_type(8))) short short8v;   // 8 bf16 = 4 VGPR
typedef __attribute__((ext_vector_type(4))) float f32x4;     // mfma accumulator

// ---------------- CSR build: histogram by dst ----------------
__global__ void hist_kernel(const int* __restrict__ ei, int* __restrict__ cnt) {
    int i = blockIdx.x * blockDim.x + threadIdx.x;
    if (i < N_EDGES) atomicAdd(&cnt[ei[N_EDGES + i]], 1);
}

__global__ __launch_bounds__(256) void scan_part(const int* __restrict__ deg,
                                                 int* __restrict__ bsums) {
    int b = blockIdx.x, t = threadIdx.x;
    int i0 = b * 1024 + t * 4;
    int s = 0;
    #pragma unroll
    for (int k = 0; k < 4; ++k) { int i = i0 + k; if (i < N_NODES) s += deg[i]; }
    #pragma unroll
    for (int off = 32; off > 0; off >>= 1) s += __shfl_down(s, off, 64);
    __shared__ int wsum[4];
    if ((t & 63) == 0) wsum[t >> 6] = s;
    __syncthreads();
    if (t == 0) bsums[b] = wsum[0] + wsum[1] + wsum[2] + wsum[3];
}

__global__ void scan_tops(int* __restrict__ bsums, int* __restrict__ ptr) {
    __shared__ int sh[128];
    int t = threadIdx.x;
    int v = (t < NB_SCAN) ? bsums[t] : 0;
    sh[t] = v;
    __syncthreads();
    for (int off = 1; off < 128; off <<= 1) {
        int a = sh[t];
        int add = (t >= off) ? sh[t - off] : 0;
        __syncthreads();
        sh[t] = a + add;
        __syncthreads();
    }
    if (t < NB_SCAN) bsums[t] = sh[t] - v;
    if (t == 127) ptr[N_NODES] = sh[127];
}

__global__ __launch_bounds__(256) void scan_fin(int* __restrict__ deg_cursor,
                                                const int* __restrict__ bsums,
                                                int* __restrict__ ptr) {
    int b = blockIdx.x, t = threadIdx.x;
    int i0 = b * 1024 + t * 4;
    int d[4]; int s = 0;
    #pragma unroll
    for (int k = 0; k < 4; ++k) {
        int i = i0 + k;
        d[k] = (i < N_NODES) ? deg_cursor[i] : 0;
        s += d[k];
    }
    __shared__ int sh[256];
    sh[t] = s;
    __syncthreads();
    for (int off = 1; off < 256; off <<= 1) {
        int a = sh[t];
        int add = (t >= off) ? sh[t - off] : 0;
        __syncthreads();
        sh[t] = a + add;
        __syncthreads();
    }
    int run = bsums[b] + sh[t] - s;
    #pragma unroll
    for (int k = 0; k < 4; ++k) {
        int i = i0 + k;
        if (i < N_NODES) { ptr[i] = run; deg_cursor[i] = run; run += d[k]; }
    }
}

__global__ void fill_kernel(const int* __restrict__ ei, int* __restrict__ cursor,
                            int* __restrict__ csr_src) {
    int i = blockIdx.x * blockDim.x + threadIdx.x;
    if (i < N_EDGES) {
        int s = ei[i];
        int d = ei[N_EDGES + i];
        int p = atomicAdd(&cursor[d], 1);
        csr_src[p] = s;
    }
}

// helpers
__device__ __forceinline__ short f2bf(float f) {
    __hip_bfloat16 h = __float2bfloat16(f);
    return *reinterpret_cast<const short*>(&h);
}
__device__ __forceinline__ float bf2f(short s) {
    return __uint_as_float(((unsigned)(unsigned short)s) << 16);
}
__device__ __forceinline__ float4 bf4_to_f4(uint2 u) {
    float4 r;
    r.x = __uint_as_float(u.x << 16);
    r.y = __uint_as_float(u.x & 0xffff0000u);
    r.z = __uint_as_float(u.y << 16);
    r.w = __uint_as_float(u.y & 0xffff0000u);
    return r;
}

// ---------------- X fp32 -> bf16 (halves layer-1 gather bytes) ----------------
__global__ void prep_x(const float* __restrict__ X, short* __restrict__ Xb) {
    int i = blockIdx.x * 256 + threadIdx.x;
    if (i < N_NODES * 64) Xb[i] = f2bf(X[i]);
}

// ---------------- weight prep: W[K][200] fp32 -> hi/lo bf16 tables [224 cols][224 k] ----------------
__global__ void prep_w(const float* __restrict__ W1a, const float* __restrict__ W1b,
                       const float* __restrict__ W2a, const float* __restrict__ W2b,
                       short* __restrict__ wt) {
    int idx = blockIdx.x * 256 + threadIdx.x;
    if (idx >= 4 * WT_PER) return;
    int tsel = idx / WT_PER, rem = idx % WT_PER;
    int c = rem / 224, k = rem % 224;
    const float* W = (tsel == 0) ? W1a : (tsel == 1) ? W1b : (tsel == 2) ? W2a : W2b;
    int K = (tsel == 0) ? 64 : 200;
    float v = (k < K && c < 200) ? W[k * 200 + c] : 0.0f;   // pads MUST be zero
    short hi = f2bf(v);
    short lo = f2bf(v - bf2f(hi));
    wt[(2 * tsel) * WT_PER + rem] = hi;
    wt[(2 * tsel + 1) * WT_PER + rem] = lo;
}

// ---- split-bf16 MFMA tile GEMM ----
// A: row=l&15, k=8*(l>>4)+j ; B: col=l&15, same k ; acc: col=l&15, row=(l>>4)*4+i
// acc += Ah*Bh + Ah*Bl + Al*Bh  (Al*Bl dropped, ~2^-16 relative)
template <int NKS>
__device__ __forceinline__ void gemm_split(const short* __restrict__ SLh,
                                           const short* __restrict__ SLl,
                                           const short* __restrict__ Wh,
                                           const short* __restrict__ Wl,
                                           int l15, int lhi, int rt,
                                           int base, int cnt, f32x4 acc[4]) {
    for (int ks = 0; ks < NKS; ++ks) {
        const int k0 = ks * 32 + 8 * lhi;
        short8v ah = *reinterpret_cast<const short8v*>(SLh + (rt * 16 + l15) * SA + k0);
        short8v al = *reinterpret_cast<const short8v*>(SLl + (rt * 16 + l15) * SA + k0);
        #pragma unroll
        for (int i = 0; i < 4; ++i) {
            if (i < cnt) {
                const int wrow = (base + i) * 16 + l15;
                short8v bh = *reinterpret_cast<const short8v*>(Wh + wrow * 224 + k0);
                short8v bl = *reinterpret_cast<const short8v*>(Wl + wrow * 224 + k0);
                acc[i] = __builtin_amdgcn_mfma_f32_16x16x32_bf16(ah, bh, acc[i], 0, 0, 0);
                acc[i] = __builtin_amdgcn_mfma_f32_16x16x32_bf16(ah, bl, acc[i], 0, 0, 0);
                acc[i] = __builtin_amdgcn_mfma_f32_16x16x32_bf16(al, bh, acc[i], 0, 0, 0);
            }
        }
    }
}

// ---------------- fused GIN layer: gather -> split-MFMA GEMM1 -> relu -> GEMM2 -> BN ----------------
// 1024 threads = 16 waves; 64 nodes/block; LDS 59.4KB -> 2 blocks/CU = 32 waves/CU.
// ONE acc[4] (16 AGPRs) reused for both GEMMs — under the 64-reg cap of (1024,8)
// this leaves 48 arch-VGPRs for the gather (round-7 lesson: two acc arrays = 32 AGPR
// pinned kernel-wide -> only 32 VGPRs -> phase-boundary scratch spills).
template <bool FIRST>
__global__ __launch_bounds__(1024, 8) void gin_mfma(
        const void* __restrict__ Xv,                 // bf16 [N][64] or bf16 [N][200]
        const int* __restrict__ ptr, const int* __restrict__ srcl,
        const float* __restrict__ eps_p,
        const short* __restrict__ Wa2,               // hi table; lo at +WT_PER
        const float* __restrict__ ba,
        const short* __restrict__ Wb2, const float* __restrict__ bb,
        const float* __restrict__ gamma, const float* __restrict__ beta,
        const float* __restrict__ mean, const float* __restrict__ var,
        void* __restrict__ outv) {                   // bf16 [N][200] or fp32 [N][200]
    __shared__ __align__(16) short SLh[64 * SA];     // 29,696 B
    __shared__ __align__(16) short SLl[64 * SA];     // 29,696 B
    const int t = threadIdx.x;
    const int lane = t & 63;
    const int wid = t >> 6;
    const int node0 = blockIdx.x * 64;
    const float ep = 1.0f + eps_p[0];

    // ---- zero the k-pad cols [200,232) so garbage never reaches MFMA ----
    for (int i = t; i < 64 * 32; i += 1024) {
        int row = i >> 5, c = 200 + (i & 31);
        SLh[row * SA + c] = 0;
        SLl[row * SA + c] = 0;
    }

    // ---- gather phase: 4 rows per wave, 4-deep ILP, 2 accumulators ----
    if (FIRST) {
        const short* Xb = (const short*)Xv;          // bf16 [N][64]
        for (int rr = 0; rr < 4; ++rr) {
            int row = wid * 4 + rr;
            int node = node0 + row;
            if (node >= N_NODES) break;
            int b = ptr[node], e = ptr[node + 1];
            float a0 = ep * bf2f(Xb[(size_t)node * 64 + lane]);
            float a1 = 0.f;
            int j = b;
            for (; j + 4 <= e; j += 4) {
                int s0 = srcl[j+0], s1 = srcl[j+1], s2 = srcl[j+2], s3 = srcl[j+3];
                short f0 = Xb[(size_t)s0 * 64 + lane];
                short f1 = Xb[(size_t)s1 * 64 + lane];
                short f2 = Xb[(size_t)s2 * 64 + lane];
                short f3 = Xb[(size_t)s3 * 64 + lane];
                a0 += bf2f(f0) + bf2f(f2);
                a1 += bf2f(f1) + bf2f(f3);
            }
            for (; j < e; ++j) a0 += bf2f(Xb[(size_t)srcl[j] * 64 + lane]);
            float s = a0 + a1;
            short hi = f2bf(s);
            SLh[row * SA + lane] = hi;               // k = lane < 64
            SLl[row * SA + lane] = f2bf(s - bf2f(hi));
        }
    } else {
        const uint2* H2 = (const uint2*)Xv;          // bf16 rows: 50 x uint2
        for (int rr = 0; rr < 4; ++rr) {
            int row = wid * 4 + rr;
            int node = node0 + row;
            if (node >= N_NODES) break;
            int b = ptr[node], e = ptr[node + 1];
            if (lane < 50) {
                float4 fs = bf4_to_f4(H2[(size_t)node * 50 + lane]);
                float4 A0 = make_float4(ep * fs.x, ep * fs.y, ep * fs.z, ep * fs.w);
                float4 A1 = make_float4(0.f, 0.f, 0.f, 0.f);
                int j = b;
                for (; j + 4 <= e; j += 4) {
                    int s0 = srcl[j+0], s1 = srcl[j+1], s2 = srcl[j+2], s3 = srcl[j+3];
                    uint2 u0 = H2[(size_t)s0 * 50 + lane];
                    uint2 u1 = H2[(size_t)s1 * 50 + lane];
                    uint2 u2 = H2[(size_t)s2 * 50 + lane];
                    uint2 u3 = H2[(size_t)s3 * 50 + lane];
                    float4 f0 = bf4_to_f4(u0), f1 = bf4_to_f4(u1);
                    float4 f2 = bf4_to_f4(u2), f3 = bf4_to_f4(u3);
                    A0.x += f0.x + f2.x; A0.y += f0.y + f2.y;
                    A0.z += f0.z + f2.z; A0.w += f0.w + f2.w;
                    A1.x += f1.x + f3.x; A1.y += f1.y + f3.y;
                    A1.z += f1.z + f3.z; A1.w += f1.w + f3.w;
                }
                for (; j < e; ++j) {
                    float4 f0 = bf4_to_f4(H2[(size_t)srcl[j] * 50 + lane]);
                    A0.x += f0.x; A0.y += f0.y; A0.z += f0.z; A0.w += f0.w;
                }
                float sx = A0.x + A1.x;
                float sy = A0.y + A1.y;
                float sz = A0.z + A1.z;
                float sw = A0.w + A1.w;
                short4 ph, pl;
                ph.x = f2bf(sx); pl.x = f2bf(sx - bf2f(ph.x));
                ph.y = f2bf(sy); pl.y = f2bf(sy - bf2f(ph.y));
                ph.z = f2bf(sz); pl.z = f2bf(sz - bf2f(ph.z));
                ph.w = f2bf(sw); pl.w = f2bf(sw - bf2f(ph.w));
                *reinterpret_cast<short4*>(&SLh[row * SA + 4 * lane]) = ph;
                *reinterpret_cast<short4*>(&SLl[row * SA + 4 * lane]) = pl;
            }
        }
    }
    __syncthreads();

    const int l15 = lane & 15;
    const int lhi = lane >> 4;
    const int rt = wid >> 2;                         // row-tile 0..3
    const int cq = wid & 3;                          // col-group 0..3
    const int base = (cq == 0) ? 0 : (4 + 3 * (cq - 1));   // {0,4,7,10}
    const int cnt  = (cq == 0) ? 4 : 3;                    // 4+3+3+3 = 13 col-tiles

    // ---- single accumulator, reused by both GEMMs (16 AGPRs total) ----
    f32x4 acc[4];

    // ---- GEMM1 ----
    #pragma unroll
    for (int i = 0; i < 4; ++i) acc[i] = (f32x4){0.f, 0.f, 0.f, 0.f};
    if (FIRST) gemm_split<2>(SLh, SLl, Wa2, Wa2 + WT_PER, l15, lhi, rt, base, cnt, acc);
    else       gemm_split<7>(SLh, SLl, Wa2, Wa2 + WT_PER, l15, lhi, rt, base, cnt, acc);
    __syncthreads();   // all A1 reads done before overwrite

    // ---- t = relu(acc + ba) -> SLh/SLl (cols < 200; pads still zero) ----
    #pragma unroll
    for (int i = 0; i < 4; ++i) {
        if (i < cnt) {
            int col = (base + i) * 16 + l15;
            if (col < 200) {
                float bv = ba[col];
                #pragma unroll
                for (int r = 0; r < 4; ++r) {
                    int row = rt * 16 + lhi * 4 + r;
                    float v = fmaxf(acc[i][r] + bv, 0.0f);
                    short hi = f2bf(v);
                    SLh[row * SA + col] = hi;
                    SLl[row * SA + col] = f2bf(v - bf2f(hi));
                }
            }
        }
    }
    __syncthreads();

    // ---- GEMM2 (K = 200 both layers), same acc re-zeroed ----
    #pragma unroll
    for (int i = 0; i < 4; ++i) acc[i] = (f32x4){0.f, 0.f, 0.f, 0.f};
    gemm_split<7>(SLh, SLl, Wb2, Wb2 + WT_PER, l15, lhi, rt, base, cnt, acc);

    // ---- epilogue: relu + BN -> out ----
    #pragma unroll
    for (int i = 0; i < 4; ++i) {
        if (i < cnt) {
            int col = (base + i) * 16 + l15;
            if (col < 200) {
                float bv = bb[col];
                float g0 = gamma[col], bt = beta[col], mn = mean[col];
                float inv = rsqrtf(var[col] + 1e-5f);
                #pragma unroll
                for (int r = 0; r < 4; ++r) {
                    int row = rt * 16 + lhi * 4 + r;
                    int node = node0 + row;
                    if (node < N_NODES) {
                        float v = fmaxf(acc[i][r] + bv, 0.0f);
                        v = (v - mn) * inv * g0 + bt;
                        if (FIRST) ((__hip_bfloat16*)outv)[(size_t)node * 200 + col] = __float2bfloat16(v);
                        else       ((float*)outv)[(size_t)node * 200 + col] = v;
                    }
                }
            }
        }
    }
}

// ---------------- fused pooling (sum+max) + FC + log_softmax ----------------
__device__ __forceinline__ int lower_bound_dev(const int* a, int n, int v) {
    int lo = 0, hi = n;
    while (lo < hi) { int mid = (lo + hi) >> 1; if (a[mid] < v) lo = mid + 1; else hi = mid; }
    return lo;
}

__global__ __launch_bounds__(256) void pool_fc_kernel(const float* __restrict__ h,
        const int* __restrict__ batch, const float* __restrict__ Wfc,
        const float* __restrict__ bfc, float* __restrict__ out) {
    int g = blockIdx.x;
    __shared__ int range[2];
    if (threadIdx.x == 0) range[0] = lower_bound_dev(batch, N_NODES, g);
    else if (threadIdx.x == 64) range[1] = lower_bound_dev(batch, N_NODES, g + 1);
    __syncthreads();
    int b = range[0], e = range[1];
    int d = threadIdx.x;
    float s0 = 0.f, s1 = 0.f, s2 = 0.f, s3 = 0.f, m = -3.0e38f;
    int n = b;
    if (d < 200) {
        for (; n + 4 <= e; n += 4) {   // 4 independent row-streams
            float v0 = h[(size_t)(n+0) * 200 + d];
            float v1 = h[(size_t)(n+1) * 200 + d];
            float v2 = h[(size_t)(n+2) * 200 + d];
            float v3 = h[(size_t)(n+3) * 200 + d];
            s0 += v0; s1 += v1; s2 += v2; s3 += v3;
            m = fmaxf(m, fmaxf(fmaxf(v0, v1), fmaxf(v2, v3)));
        }
        for (; n < e; ++n) {
            float v = h[(size_t)n * 200 + d];
            s0 += v;
            m = fmaxf(m, v);
        }
    }
    float s = (s0 + s1) + (s2 + s3);
    float c0 = 0.f, c1 = 0.f;
    if (d < 200) {
        c0 = s * Wfc[d * 2 + 0] + m * Wfc[(200 + d) * 2 + 0];
        c1 = s * Wfc[d * 2 + 1] + m * Wfc[(200 + d) * 2 + 1];
    }
    #pragma unroll
    for (int off = 32; off > 0; off >>= 1) {
        c0 += __shfl_down(c0, off, 64);
        c1 += __shfl_down(c1, off, 64);
    }
    __shared__ float r0[4], r1[4];
    int wid = threadIdx.x >> 6;
    if ((threadIdx.x & 63) == 0) { r0[wid] = c0; r1[wid] = c1; }
    __syncthreads();
    if (threadIdx.x == 0) {
        float l0 = r0[0] + r0[1] + r0[2] + r0[3] + bfc[0];
        float l1 = r1[0] + r1[1] + r1[2] + r1[3] + bfc[1];
        float mx = fmaxf(l0, l1);
        float lse = mx + logf(expf(l0 - mx) + expf(l1 - mx));
        out[g * 2 + 0] = l0 - lse;
        out[g * 2 + 1] = l1 - lse;
    }
}

// ---------------- launch ----------------
extern "C" void kernel_launch(void* const* d_in, const int* in_sizes, int n_in,
                              void* d_out, int out_size, void* d_ws, size_t ws_size,
                              hipStream_t stream) {
    const float* x    = (const float*)d_in[0];
    const int*   ei   = (const int*)d_in[1];
    const int*   batch= (const int*)d_in[2];
    const float* eps1 = (const float*)d_in[3];
    const float* W1a  = (const float*)d_in[4];
    const float* b1a  = (const float*)d_in[5];
    const float* W1b  = (const float*)d_in[6];
    const float* b1b  = (const float*)d_in[7];
    const float* bn1g = (const float*)d_in[8];
    const float* bn1b = (const float*)d_in[9];
    const float* bn1m = (const float*)d_in[10];
    const float* bn1v = (const float*)d_in[11];
    const float* eps2 = (const float*)d_in[12];
    const float* W2a  = (const float*)d_in[13];
    const float* b2a  = (const float*)d_in[14];
    const float* W2b  = (const float*)d_in[15];
    const float* b2b  = (const float*)d_in[16];
    const float* bn2g = (const float*)d_in[17];
    const float* bn2b = (const float*)d_in[18];
    const float* bn2m = (const float*)d_in[19];
    const float* bn2v = (const float*)d_in[20];
    const float* Wfc  = (const float*)d_in[21];
    const float* bfc  = (const float*)d_in[22];
    float* out = (float*)d_out;

    // workspace layout (~141 MB total):
    // [0, 400128)               csr_ptr (N+1 ints)
    // [400128, 800256)          cursor
    // [800256, 7200256)         csr_src (E ints)
    // [7200256, 8003072)        wt: 8 bf16 tables [224][224] (hi/lo x 4 matrices)
    // [8003072, 20803072)       Xb (N x 64 bf16)
    // [20803072, 60803072)      h1b (N x 200 bf16)
    // [60803072, 140803072)     h2  (N x 200 fp32)
    char* ws = (char*)d_ws;
    int* csr_ptr = (int*)(ws + 0);
    int* cursor  = (int*)(ws + 400128);
    int* csr_src = (int*)(ws + 800256);
    short* wt    = (short*)(ws + 7200256);
    short* W1a2 = wt;                    // hi; lo at +WT_PER
    short* W1b2 = wt + 2 * WT_PER;
    short* W2a2 = wt + 4 * WT_PER;
    short* W2b2 = wt + 6 * WT_PER;
    short* Xb    = (short*)(ws + 8003072);
    __hip_bfloat16* h1b = (__hip_bfloat16*)(ws + 20803072);
    float* h2    = (float*)(ws + 60803072);
    int* bsums   = (int*)(ws + 20803072);  // alias h1b: dead until layer1 writes

    hipMemsetAsync(cursor, 0, N_NODES * sizeof(int), stream);
    hist_kernel<<<(N_EDGES + 255) / 256, 256, 0, stream>>>(ei, cursor);
    scan_part<<<NB_SCAN, 256, 0, stream>>>(cursor, bsums);
    scan_tops<<<1, 128, 0, stream>>>(bsums, csr_ptr);
    scan_fin<<<NB_SCAN, 256, 0, stream>>>(cursor, bsums, csr_ptr);
    fill_kernel<<<(N_EDGES + 255) / 256, 256, 0, stream>>>(ei, cursor, csr_src);
    prep_w<<<(4 * WT_PER + 255) / 256, 256, 0, stream>>>(W1a, W1b, W2a, W2b, wt);
    prep_x<<<(N_NODES * 64 + 255) / 256, 256, 0, stream>>>(x, Xb);

    const int NBLK = (N_NODES + 63) / 64;   // 1563
    gin_mfma<true><<<NBLK, 1024, 0, stream>>>(Xb, csr_ptr, csr_src, eps1,
            W1a2, b1a, W1b2, b1b, bn1g, bn1b, bn1m, bn1v, h1b);
    gin_mfma<false><<<NBLK, 1024, 0, stream>>>(h1b, csr_ptr, csr_src, eps2,
            W2a2, b2a, W2b2, b2b, bn2g, bn2b, bn2m, bn2v, h2);

    pool_fc_kernel<<<N_GRAPHS, 256, 0, stream>>>(h2, batch, Wfc, bfc, out);
}